// Round 13
// baseline (794.014 us; speedup 1.0000x reference)
//
#include <hip/hip_runtime.h>

// SPModel_6846177870356: y = x@W^T + all2all permute. M=28160, N=K=2048.
// Inputs FP32 (harness-upcast fp16), output FP32.
// Round 13: 256x256, BK=64, dbuf, FOUR phases per K-tile (m201-style):
// per phase: vmcnt(0) gate -> s_barrier -> stage 2x8KB units (tile t+1) ->
// ds_read next-quadrant frags -> setprio(1) 16 MFMA setprio(0).
// Quadrant order (qm,qn): (0,0),(1,0),(1,1),(0,1); stage order {B01,B23,
// A02,A13} gives >=1-phase landing lead before each unit's gated first read.
// A[qm=0] re-read at q2 (VGPR budget); even/odd tiles swap A-reg roles.
// Pre-swizzled f16 global copies (R9), conflict-free XOR ds_read, XCD swizzle,
// fused all2all f32 epilogue.

typedef _Float16 f16;
typedef _Float16 f16x2 __attribute__((ext_vector_type(2)));
typedef _Float16 f16x8 __attribute__((ext_vector_type(8)));
typedef float    f32x4 __attribute__((ext_vector_type(4)));

#define GPTR(p) ((const __attribute__((address_space(1))) void*)(p))
#define LPTR(p) ((__attribute__((address_space(3))) void*)(p))

constexpr int Mdim = 28160;   // 8*44*80
constexpr int Ndim = 2048;
constexpr int Kdim = 2048;
constexpr int BM = 256, BN = 256, BK = 64;
constexpr int NWG = (Mdim / BM) * (Ndim / BN);  // 880 (%8==0)
constexpr int NT  = Kdim / BK;                  // 32 (even)
constexpr size_t XS_ELEMS = (size_t)Mdim * Kdim;
constexpr size_t WS_ELEMS = (size_t)Ndim * Kdim;
constexpr size_t WS_NEED  = (XS_ELEMS + WS_ELEMS) * sizeof(f16);

__device__ __forceinline__ f16x8 pack8(const f32x4& lo, const f32x4& hi) {
    f16x2 p0 = __builtin_bit_cast(f16x2, __builtin_amdgcn_cvt_pkrtz(lo[0], lo[1]));
    f16x2 p1 = __builtin_bit_cast(f16x2, __builtin_amdgcn_cvt_pkrtz(lo[2], lo[3]));
    f16x2 p2 = __builtin_bit_cast(f16x2, __builtin_amdgcn_cvt_pkrtz(hi[0], hi[1]));
    f16x2 p3 = __builtin_bit_cast(f16x2, __builtin_amdgcn_cvt_pkrtz(hi[2], hi[3]));
    return (f16x8){p0[0], p0[1], p1[0], p1[1], p2[0], p2[1], p3[0], p3[1]};
}

// f32 [rows x 2048] -> f16 pre-swizzled: dst[m][(k8 ^ (m&7))*8] (R9-verified).
__global__ __launch_bounds__(256)
void convert_kernel(const float* __restrict__ src, f16* __restrict__ dst) {
    const int idx = blockIdx.x * 256 + threadIdx.x;
    const int m   = idx >> 8;
    const int k8  = idx & 255;
    const int k8s = k8 ^ (m & 7);
    const float* p = src + (size_t)m * Kdim + k8 * 8;
    f32x4 lo = *(const f32x4*)p;
    f32x4 hi = *(const f32x4*)(p + 4);
    *(f16x8*)(dst + (size_t)m * Kdim + k8s * 8) = pack8(lo, hi);
}

// swizzled LDS read: row stride 128B, byte ^= (row&7)<<4 (0 conflicts, R9/R12)
__device__ __forceinline__ f16x8 lds_frag(const f16* base, int r, int kc) {
    const int b = ((r * BK + kc) * 2) ^ ((r & 7) << 4);
    return *(const f16x8*)((const char*)base + b);
}

#define GATE() do { asm volatile("s_waitcnt vmcnt(0)" ::: "memory"); \
                    __builtin_amdgcn_s_barrier(); \
                    __builtin_amdgcn_sched_barrier(0); } while (0)

__global__ __launch_bounds__(512, 2)
void gemm_a2a_kernel(const f16* __restrict__ Xs, const f16* __restrict__ Ws,
                     float* __restrict__ out) {
    __shared__ f16 sA[2][BM * BK];   // 32 KiB each (swizzled image)
    __shared__ f16 sB[2][BN * BK];   // total 128 KiB

    const int tid  = threadIdx.x;
    const int lane = tid & 63;
    const int wid  = tid >> 6;
    const int wm   = wid >> 2;          // 0..1 -> 128 M-rows
    const int wn   = wid & 3;           // 0..3 -> 64 N-cols

    const int cpx  = NWG >> 3;                       // XCD-bijective swizzle
    const int tile = (blockIdx.x & 7) * cpx + (blockIdx.x >> 3);
    const int bn   = tile & 7;
    const int bm   = tile >> 3;
    const int row0 = bm * BM;
    const int col0 = bn * BN;

    const int lr = lane & 15;
    const int kq = (lane >> 4) * 8;

    f32x4 acc[8][4] = {};

    // unit = 64 rows x 64 k = 8KB; chunk c = tid; LDS linear within unit.
    const int ur = tid >> 3;            // row within unit (0..63)
    const int uk = (tid & 7) * 8;       // k offset (pre-swizzled source)
    auto stageA = [&](int t, int d, int i) {
        __builtin_amdgcn_global_load_lds(
            GPTR(Xs + (size_t)(row0 + i * 64 + ur) * Kdim + t * BK + uk),
            LPTR(&sA[d][i * 4096 + tid * 8]), 16, 0, 0);
    };
    auto stageB = [&](int t, int d, int i) {
        __builtin_amdgcn_global_load_lds(
            GPTR(Ws + (size_t)(col0 + i * 64 + ur) * Kdim + t * BK + uk),
            LPTR(&sB[d][i * 4096 + tid * 8]), 16, 0, 0);
    };

    f16x8 Aa[4][2], Ab[4][2], Ba[2][2], Bb[2][2];
    auto readA = [&](const f16* base, int qm, f16x8 (&dst)[4][2]) {
#pragma unroll
        for (int f = 0; f < 4; ++f)
#pragma unroll
            for (int kk = 0; kk < 2; ++kk)
                dst[f][kk] = lds_frag(base, wm * 128 + qm * 64 + f * 16 + lr,
                                      kk * 32 + kq);
    };
    auto readB = [&](const f16* base, int qn, f16x8 (&dst)[2][2]) {
#pragma unroll
        for (int g = 0; g < 2; ++g)
#pragma unroll
            for (int kk = 0; kk < 2; ++kk)
                dst[g][kk] = lds_frag(base, wn * 64 + qn * 32 + g * 16 + lr,
                                      kk * 32 + kq);
    };

#define MFMA16(ASET, BSET, QM, QN)                                          \
    do {                                                                    \
        __builtin_amdgcn_s_setprio(1);                                      \
        _Pragma("unroll")                                                   \
        for (int f = 0; f < 4; ++f)                                         \
            _Pragma("unroll")                                               \
            for (int g = 0; g < 2; ++g)                                     \
                _Pragma("unroll")                                           \
                for (int kk = 0; kk < 2; ++kk)                              \
                    acc[(QM)*4 + f][(QN)*2 + g] =                           \
                        __builtin_amdgcn_mfma_f32_16x16x32_f16(             \
                            ASET[f][kk], BSET[g][kk],                       \
                            acc[(QM)*4 + f][(QN)*2 + g], 0, 0, 0);          \
        __builtin_amdgcn_s_setprio(0);                                      \
    } while (0)

    // Prologue: stage full tile 0 -> buf0; certify; preload q0 frags.
#pragma unroll
    for (int i = 0; i < 4; ++i) { stageA(0, 0, i); stageB(0, 0, i); }
    asm volatile("s_waitcnt vmcnt(0)" ::: "memory");
    __builtin_amdgcn_s_barrier();
    readA(sA[0], 0, Aa);
    readB(sB[0], 0, Ba);

    // Tile body: A1ST holds A[qm=0] entering the tile; ends with A2ND=A0(t+1),
    // Ba=B0(t+1). Even tiles: (Aa,Ab); odd: (Ab,Aa).
#define TILE_BODY(T, A1ST, A2ND)                                            \
    do {                                                                    \
        const int d  = (T) & 1;                                             \
        const int tn = ((T) + 1 < NT) ? (T) + 1 : (T);                      \
        const f16* Abuf = sA[d];                                            \
        const f16* Bbuf = sB[d];                                            \
        /* q0 (0,0) */                                                      \
        GATE(); stageB(tn, d ^ 1, 0); stageB(tn, d ^ 1, 1);                 \
        readA(Abuf, 1, A2ND);                                               \
        MFMA16(A1ST, Ba, 0, 0);                                             \
        /* q1 (1,0) */                                                      \
        GATE(); stageB(tn, d ^ 1, 2); stageB(tn, d ^ 1, 3);                 \
        readB(Bbuf, 1, Bb);                                                 \
        MFMA16(A2ND, Ba, 1, 0);                                             \
        /* q2 (1,1) */                                                      \
        GATE(); stageA(tn, d ^ 1, 0); stageA(tn, d ^ 1, 2);                 \
        readA(Abuf, 0, A1ST);                                               \
        MFMA16(A2ND, Bb, 1, 1);                                             \
        /* q3 (0,1) */                                                      \
        GATE(); stageA(tn, d ^ 1, 1); stageA(tn, d ^ 1, 3);                 \
        readA(sA[d ^ 1], 0, A2ND);                                          \
        readB(sB[d ^ 1], 0, Ba);                                            \
        MFMA16(A1ST, Bb, 0, 1);                                             \
    } while (0)

    for (int t = 0; t < NT; t += 2) {
        TILE_BODY(t,     Aa, Ab);
        TILE_BODY(t + 1, Ab, Aa);
    }

    // Epilogue: C/D col=lane&15 (n), row=(lane>>4)*4+j (m); fused all2all:
    // out[(n>>8)*M*256 + m*256 + (n&255)], f32 stores.
    const int R0 = row0 + wm * 128;
    const int C0 = col0 + wn * 64;
#pragma unroll
    for (int mi = 0; mi < 8; ++mi)
#pragma unroll
        for (int ni = 0; ni < 4; ++ni) {
            const int n     = C0 + ni * 16 + (lane & 15);
            const int rbase = R0 + mi * 16 + (lane >> 4) * 4;
            const size_t obase = (size_t)(n >> 8) * ((size_t)Mdim * 256) + (n & 255);
#pragma unroll
            for (int j = 0; j < 4; ++j)
                out[obase + (size_t)(rbase + j) * 256] = acc[mi][ni][j];
        }
}

// ---- Fallback (R7-verified): direct-f32 reg-staged dbuf 128^2 kernel ----
constexpr int FBM = 128, FBK = 64;
constexpr int FNWG = (Mdim / FBM) * (Ndim / FBM);
__global__ __launch_bounds__(256)
void gemm_a2a_f32_kernel(const float* __restrict__ X, const float* __restrict__ W,
                         float* __restrict__ out) {
    __shared__ f16 sA[2][FBM * FBK];
    __shared__ f16 sB[2][FBM * FBK];
    const int tid  = threadIdx.x;
    const int lane = tid & 63;
    const int wid  = tid >> 6;
    const int wr   = wid >> 1;
    const int wc   = wid & 1;
    const int cpx  = FNWG >> 3;
    const int tile = (blockIdx.x & 7) * cpx + (blockIdx.x >> 3);
    const int bn   = tile & 15;
    const int bm   = tile >> 4;
    const int row0 = bm * FBM;
    const int col0 = bn * FBM;
    f32x4 acc[4][4] = {};
    f32x4 ra[8], rb[8];
    auto load_tile = [&](int t) {
#pragma unroll
        for (int i = 0; i < 4; ++i) {
            const int c8 = i * 256 + tid;
            const int r  = c8 >> 3;
            const int cc = (c8 & 7) * 8;
            const float* pa = X + (size_t)(row0 + r) * Kdim + t * FBK + cc;
            const float* pb = W + (size_t)(col0 + r) * Kdim + t * FBK + cc;
            ra[2*i] = *(const f32x4*)pa; ra[2*i+1] = *(const f32x4*)(pa + 4);
            rb[2*i] = *(const f32x4*)pb; rb[2*i+1] = *(const f32x4*)(pb + 4);
        }
    };
    int cur = 0;
    load_tile(0);
    for (int t = 0; t < Kdim / FBK; ++t) {
#pragma unroll
        for (int i = 0; i < 4; ++i) {
            const int c8 = i * 256 + tid;
            const int sb = (c8 * 16) ^ (((c8 >> 3) & 7) << 4);
            *(f16x8*)((char*)sA[cur] + sb) = pack8(ra[2*i], ra[2*i+1]);
            *(f16x8*)((char*)sB[cur] + sb) = pack8(rb[2*i], rb[2*i+1]);
        }
        if (t + 1 < Kdim / FBK) load_tile(t + 1);
        __syncthreads();
        const f16* Ab = sA[cur];
        const f16* Bb = sB[cur];
#pragma unroll
        for (int kk = 0; kk < FBK; kk += 32) {
            const int kc = kk + (lane >> 4) * 8;
            f16x8 af[4], bfr[4];
#pragma unroll
            for (int f = 0; f < 4; ++f) {
                const int rowA = wr * 64 + f * 16 + (lane & 15);
                af[f] = *(const f16x8*)((const char*)Ab + (((rowA * FBK + kc) * 2) ^ ((rowA & 7) << 4)));
                const int rowB = wc * 64 + f * 16 + (lane & 15);
                bfr[f] = *(const f16x8*)((const char*)Bb + (((rowB * FBK + kc) * 2) ^ ((rowB & 7) << 4)));
            }
#pragma unroll
            for (int mi = 0; mi < 4; ++mi)
#pragma unroll
                for (int ni = 0; ni < 4; ++ni)
                    acc[mi][ni] = __builtin_amdgcn_mfma_f32_16x16x32_f16(
                        af[mi], bfr[ni], acc[mi][ni], 0, 0, 0);
        }
        cur ^= 1;
    }
#pragma unroll
    for (int mi = 0; mi < 4; ++mi)
#pragma unroll
        for (int ni = 0; ni < 4; ++ni) {
            const int n     = col0 + wc * 64 + ni * 16 + (lane & 15);
            const int rbase = row0 + wr * 64 + mi * 16 + (lane >> 4) * 4;
            const size_t obase = (size_t)(n >> 8) * ((size_t)Mdim * 256) + (n & 255);
#pragma unroll
            for (int j = 0; j < 4; ++j)
                out[obase + (size_t)(rbase + j) * 256] = acc[mi][ni][j];
        }
}

extern "C" void kernel_launch(void* const* d_in, const int* in_sizes, int n_in,
                              void* d_out, int out_size, void* d_ws, size_t ws_size,
                              hipStream_t stream) {
    const float* X = (const float*)d_in[0];
    const float* W = (const float*)d_in[1];
    float* out     = (float*)d_out;
    if (ws_size >= WS_NEED) {
        f16* Xs = (f16*)d_ws;
        f16* Ws = Xs + XS_ELEMS;
        hipLaunchKernelGGL(convert_kernel, dim3((int)(XS_ELEMS / 8 / 256)), dim3(256),
                           0, stream, X, Xs);
        hipLaunchKernelGGL(convert_kernel, dim3((int)(WS_ELEMS / 8 / 256)), dim3(256),
                           0, stream, W, Ws);
        hipLaunchKernelGGL(gemm_a2a_kernel, dim3(NWG), dim3(512), 0, stream, Xs, Ws, out);
    } else {
        hipLaunchKernelGGL(gemm_a2a_f32_kernel, dim3(FNWG), dim3(256), 0, stream, X, W, out);
    }
}

// Round 14
// 447.120 us; speedup vs baseline: 1.7758x; 1.7758x over previous
//
#include <hip/hip_runtime.h>

// SPModel_6846177870356: y = x@W^T + all2all permute. M=28160, N=K=2048.
// Inputs FP32 (harness-upcast fp16), output FP32.
// Round 14: m201-faithful 4-phase schedule, spill-free (R13 lesson: NO
// cross-phase frag prefetch — read-then-consume per phase).
//  - staging units = quadrant halves: A_u{0,1} by qm, B_u{0,1} by qn
//    (16KB each, wave-linear LDS dst), order A_u0,B_u0,A_u1,B_u1
//  - per-phase gate vmcnt(4),(4),(4),none — never 0 in loop (T4);
//    one s_barrier per phase; stage t+1's unit p each phase
//  - frags: one A set + one B set, each reused across exactly one phase
//  - MFMA kk-outermost (acc reuse distance 8), setprio around cluster (T5)
//  - pre-swizzled f16 global copies (R9), conflict-free XOR ds_read (T2),
//    XCD-bijective swizzle (T1), fused all2all f32 epilogue.

typedef _Float16 f16;
typedef _Float16 f16x2 __attribute__((ext_vector_type(2)));
typedef _Float16 f16x8 __attribute__((ext_vector_type(8)));
typedef float    f32x4 __attribute__((ext_vector_type(4)));

#define GPTR(p) ((const __attribute__((address_space(1))) void*)(p))
#define LPTR(p) ((__attribute__((address_space(3))) void*)(p))

constexpr int Mdim = 28160;   // 8*44*80
constexpr int Ndim = 2048;
constexpr int Kdim = 2048;
constexpr int BM = 256, BN = 256, BK = 64;
constexpr int NWG = (Mdim / BM) * (Ndim / BN);  // 880 (%8==0)
constexpr int NT  = Kdim / BK;                  // 32
constexpr size_t XS_ELEMS = (size_t)Mdim * Kdim;
constexpr size_t WS_ELEMS = (size_t)Ndim * Kdim;
constexpr size_t WS_NEED  = (XS_ELEMS + WS_ELEMS) * sizeof(f16);

__device__ __forceinline__ f16x8 pack8(const f32x4& lo, const f32x4& hi) {
    f16x2 p0 = __builtin_bit_cast(f16x2, __builtin_amdgcn_cvt_pkrtz(lo[0], lo[1]));
    f16x2 p1 = __builtin_bit_cast(f16x2, __builtin_amdgcn_cvt_pkrtz(lo[2], lo[3]));
    f16x2 p2 = __builtin_bit_cast(f16x2, __builtin_amdgcn_cvt_pkrtz(hi[0], hi[1]));
    f16x2 p3 = __builtin_bit_cast(f16x2, __builtin_amdgcn_cvt_pkrtz(hi[2], hi[3]));
    return (f16x8){p0[0], p0[1], p1[0], p1[1], p2[0], p2[1], p3[0], p3[1]};
}

// f32 [rows x 2048] -> f16 pre-swizzled: dst[m][(k8 ^ (m&7))*8] (R9-verified).
__global__ __launch_bounds__(256)
void convert_kernel(const float* __restrict__ src, f16* __restrict__ dst) {
    const int idx = blockIdx.x * 256 + threadIdx.x;
    const int m   = idx >> 8;
    const int k8  = idx & 255;
    const int k8s = k8 ^ (m & 7);
    const float* p = src + (size_t)m * Kdim + k8 * 8;
    f32x4 lo = *(const f32x4*)p;
    f32x4 hi = *(const f32x4*)(p + 4);
    *(f16x8*)(dst + (size_t)m * Kdim + k8s * 8) = pack8(lo, hi);
}

// swizzled LDS read: row stride 128B, byte ^= (row&7)<<4 (0 conflicts)
__device__ __forceinline__ f16x8 lds_frag(const f16* base, int r, int kc) {
    const int b = ((r * BK + kc) * 2) ^ ((r & 7) << 4);
    return *(const f16x8*)((const char*)base + b);
}

__global__ __launch_bounds__(512, 2)
void gemm_a2a_kernel(const f16* __restrict__ Xs, const f16* __restrict__ Ws,
                     float* __restrict__ out) {
    __shared__ f16 sA[2][BM * BK];   // 32 KiB each, full swizzled image
    __shared__ f16 sB[2][BN * BK];   // total 128 KiB

    const int tid  = threadIdx.x;
    const int lane = tid & 63;
    const int wid  = tid >> 6;
    const int wm   = wid >> 2;          // 0..1 -> 128 M-rows
    const int wn   = wid & 3;           // 0..3 -> 64 N-cols

    const int cpx  = NWG >> 3;                       // XCD-bijective swizzle
    const int tile = (blockIdx.x & 7) * cpx + (blockIdx.x >> 3);
    const int bn   = tile & 7;
    const int bm   = tile >> 3;
    const int row0 = bm * BM;
    const int col0 = bn * BN;

    const int lr = lane & 15;
    const int kq = (lane >> 4) * 8;

    f32x4 acc[8][4] = {};

    // --- staging pre-computation (unit u, issue-group g) ---
    // A unit u rows: u*64 + {0..63} and 128 + u*64 + {0..63}  (qm halves)
    // B unit u rows: (rl&31) + u*32 + (rl>>5)*64              (qn halves)
    const f16* srcA[2][2]; const f16* srcB[2][2];
    int dstA[2][2], dstB[2][2];
#pragma unroll
    for (int u = 0; u < 2; ++u)
#pragma unroll
        for (int g = 0; g < 2; ++g) {
            const int L  = g * 512 + tid;
            const int rl = L >> 3;
            const int ka = (L & 7) * 8;
            const int ra = (rl & 63) + u * 64 + ((rl & 64) << 1);
            const int rb = (rl & 31) + u * 32 + ((rl >> 5) << 6);
            srcA[u][g] = Xs + (size_t)(row0 + ra) * Kdim + ka;
            srcB[u][g] = Ws + (size_t)(col0 + rb) * Kdim + ka;
            dstA[u][g] = (ra * 8 + (L & 7)) * 8;   // f16 elements
            dstB[u][g] = (rb * 8 + (L & 7)) * 8;
        }

#define STAGE_A(T, D, U)                                                     \
    do {                                                                     \
        __builtin_amdgcn_global_load_lds(GPTR(srcA[U][0] + (T) * BK),        \
            LPTR(&sA[D][dstA[U][0]]), 16, 0, 0);                             \
        __builtin_amdgcn_global_load_lds(GPTR(srcA[U][1] + (T) * BK),        \
            LPTR(&sA[D][dstA[U][1]]), 16, 0, 0);                             \
    } while (0)
#define STAGE_B(T, D, U)                                                     \
    do {                                                                     \
        __builtin_amdgcn_global_load_lds(GPTR(srcB[U][0] + (T) * BK),        \
            LPTR(&sB[D][dstB[U][0]]), 16, 0, 0);                             \
        __builtin_amdgcn_global_load_lds(GPTR(srcB[U][1] + (T) * BK),        \
            LPTR(&sB[D][dstB[U][1]]), 16, 0, 0);                             \
    } while (0)

    f16x8 Af[4][2], Bf[2][2];
    auto readA = [&](const f16* base, int qm) {
#pragma unroll
        for (int f = 0; f < 4; ++f)
#pragma unroll
            for (int kk = 0; kk < 2; ++kk)
                Af[f][kk] = lds_frag(base, wm * 128 + qm * 64 + f * 16 + lr,
                                     kk * 32 + kq);
    };
    auto readB = [&](const f16* base, int qn) {
#pragma unroll
        for (int g = 0; g < 2; ++g)
#pragma unroll
            for (int kk = 0; kk < 2; ++kk)
                Bf[g][kk] = lds_frag(base, wn * 64 + qn * 32 + g * 16 + lr,
                                     kk * 32 + kq);
    };

    // kk-outermost: 8 independent MFMAs between acc reuses
#define MFMA16(QM, QN)                                                       \
    do {                                                                     \
        __builtin_amdgcn_s_setprio(1);                                       \
        _Pragma("unroll")                                                    \
        for (int kk = 0; kk < 2; ++kk)                                       \
            _Pragma("unroll")                                                \
            for (int f = 0; f < 4; ++f)                                      \
                _Pragma("unroll")                                            \
                for (int g = 0; g < 2; ++g)                                  \
                    acc[(QM)*4 + f][(QN)*2 + g] =                            \
                        __builtin_amdgcn_mfma_f32_16x16x32_f16(              \
                            Af[f][kk], Bf[g][kk],                            \
                            acc[(QM)*4 + f][(QN)*2 + g], 0, 0, 0);           \
        __builtin_amdgcn_s_setprio(0);                                       \
    } while (0)

#define GATE4() do { asm volatile("s_waitcnt vmcnt(4)" ::: "memory");        \
                     __builtin_amdgcn_s_barrier();                           \
                     __builtin_amdgcn_sched_barrier(0); } while (0)

    // Prologue: tile 0 units in canonical queue order (A_u0,B_u0,A_u1,B_u1)
    STAGE_A(0, 0, 0); STAGE_B(0, 0, 0); STAGE_A(0, 0, 1); STAGE_B(0, 0, 1);

    for (int t = 0; t < NT - 1; ++t) {
        const int d  = t & 1;
        const int dn = d ^ 1;
        const int tn = t + 1;
        const f16* Ab = sA[d];
        const f16* Bb = sB[d];
        // p0: q(0,0) — needs A_u0(t)+B_u0(t) = oldest 4
        GATE4();
        STAGE_A(tn, dn, 0);
        readA(Ab, 0); readB(Bb, 0);
        MFMA16(0, 0);
        // p1: q(1,0) — needs A_u1(t) = oldest 2 of the remaining 6
        GATE4();
        STAGE_B(tn, dn, 0);
        readA(Ab, 1);                      // B held from p0
        MFMA16(1, 0);
        // p2: q(1,1) — needs B_u1(t)
        GATE4();
        STAGE_A(tn, dn, 1);
        readB(Bb, 1);                      // A held from p1
        MFMA16(1, 1);
        // p3: q(0,1) — all inputs already certified; no gate
        __builtin_amdgcn_s_barrier();
        __builtin_amdgcn_sched_barrier(0);
        STAGE_B(tn, dn, 1);
        readA(Ab, 0);                      // B held from p2
        MFMA16(0, 1);
    }

    // Peeled last tile: drain everything once, no staging, no inner barriers.
    {
        const int d = (NT - 1) & 1;
        const f16* Ab = sA[d];
        const f16* Bb = sB[d];
        asm volatile("s_waitcnt vmcnt(0)" ::: "memory");
        __builtin_amdgcn_s_barrier();
        __builtin_amdgcn_sched_barrier(0);
        readA(Ab, 0); readB(Bb, 0);
        MFMA16(0, 0);
        readA(Ab, 1);
        MFMA16(1, 0);
        readB(Bb, 1);
        MFMA16(1, 1);
        readA(Ab, 0);
        MFMA16(0, 1);
    }

    // Epilogue: C/D col=lane&15 (n), row=(lane>>4)*4+j (m); fused all2all:
    // out[(n>>8)*M*256 + m*256 + (n&255)], f32 stores.
    const int R0 = row0 + wm * 128;
    const int C0 = col0 + wn * 64;
#pragma unroll
    for (int mi = 0; mi < 8; ++mi)
#pragma unroll
        for (int ni = 0; ni < 4; ++ni) {
            const int n     = C0 + ni * 16 + (lane & 15);
            const int rbase = R0 + mi * 16 + (lane >> 4) * 4;
            const size_t obase = (size_t)(n >> 8) * ((size_t)Mdim * 256) + (n & 255);
#pragma unroll
            for (int j = 0; j < 4; ++j)
                out[obase + (size_t)(rbase + j) * 256] = acc[mi][ni][j];
        }
}

// ---- Fallback (R7-verified): direct-f32 reg-staged dbuf 128^2 kernel ----
constexpr int FBM = 128, FBK = 64;
constexpr int FNWG = (Mdim / FBM) * (Ndim / FBM);
__global__ __launch_bounds__(256)
void gemm_a2a_f32_kernel(const float* __restrict__ X, const float* __restrict__ W,
                         float* __restrict__ out) {
    __shared__ f16 sA[2][FBM * FBK];
    __shared__ f16 sB[2][FBM * FBK];
    const int tid  = threadIdx.x;
    const int lane = tid & 63;
    const int wid  = tid >> 6;
    const int wr   = wid >> 1;
    const int wc   = wid & 1;
    const int cpx  = FNWG >> 3;
    const int tile = (blockIdx.x & 7) * cpx + (blockIdx.x >> 3);
    const int bn   = tile & 15;
    const int bm   = tile >> 4;
    const int row0 = bm * FBM;
    const int col0 = bn * FBM;
    f32x4 acc[4][4] = {};
    f32x4 ra[8], rb[8];
    auto load_tile = [&](int t) {
#pragma unroll
        for (int i = 0; i < 4; ++i) {
            const int c8 = i * 256 + tid;
            const int r  = c8 >> 3;
            const int cc = (c8 & 7) * 8;
            const float* pa = X + (size_t)(row0 + r) * Kdim + t * FBK + cc;
            const float* pb = W + (size_t)(col0 + r) * Kdim + t * FBK + cc;
            ra[2*i] = *(const f32x4*)pa; ra[2*i+1] = *(const f32x4*)(pa + 4);
            rb[2*i] = *(const f32x4*)pb; rb[2*i+1] = *(const f32x4*)(pb + 4);
        }
    };
    int cur = 0;
    load_tile(0);
    for (int t = 0; t < Kdim / FBK; ++t) {
#pragma unroll
        for (int i = 0; i < 4; ++i) {
            const int c8 = i * 256 + tid;
            const int sb = (c8 * 16) ^ (((c8 >> 3) & 7) << 4);
            *(f16x8*)((char*)sA[cur] + sb) = pack8(ra[2*i], ra[2*i+1]);
            *(f16x8*)((char*)sB[cur] + sb) = pack8(rb[2*i], rb[2*i+1]);
        }
        if (t + 1 < Kdim / FBK) load_tile(t + 1);
        __syncthreads();
        const f16* Ab = sA[cur];
        const f16* Bb = sB[cur];
#pragma unroll
        for (int kk = 0; kk < FBK; kk += 32) {
            const int kc = kk + (lane >> 4) * 8;
            f16x8 af[4], bfr[4];
#pragma unroll
            for (int f = 0; f < 4; ++f) {
                const int rowA = wr * 64 + f * 16 + (lane & 15);
                af[f] = *(const f16x8*)((const char*)Ab + (((rowA * FBK + kc) * 2) ^ ((rowA & 7) << 4)));
                const int rowB = wc * 64 + f * 16 + (lane & 15);
                bfr[f] = *(const f16x8*)((const char*)Bb + (((rowB * FBK + kc) * 2) ^ ((rowB & 7) << 4)));
            }
#pragma unroll
            for (int mi = 0; mi < 4; ++mi)
#pragma unroll
                for (int ni = 0; ni < 4; ++ni)
                    acc[mi][ni] = __builtin_amdgcn_mfma_f32_16x16x32_f16(
                        af[mi], bfr[ni], acc[mi][ni], 0, 0, 0);
        }
        cur ^= 1;
    }
#pragma unroll
    for (int mi = 0; mi < 4; ++mi)
#pragma unroll
        for (int ni = 0; ni < 4; ++ni) {
            const int n     = col0 + wc * 64 + ni * 16 + (lane & 15);
            const int rbase = row0 + wr * 64 + mi * 16 + (lane >> 4) * 4;
            const size_t obase = (size_t)(n >> 8) * ((size_t)Mdim * 256) + (n & 255);
#pragma unroll
            for (int j = 0; j < 4; ++j)
                out[obase + (size_t)(rbase + j) * 256] = acc[mi][ni][j];
        }
}

extern "C" void kernel_launch(void* const* d_in, const int* in_sizes, int n_in,
                              void* d_out, int out_size, void* d_ws, size_t ws_size,
                              hipStream_t stream) {
    const float* X = (const float*)d_in[0];
    const float* W = (const float*)d_in[1];
    float* out     = (float*)d_out;
    if (ws_size >= WS_NEED) {
        f16* Xs = (f16*)d_ws;
        f16* Ws = Xs + XS_ELEMS;
        hipLaunchKernelGGL(convert_kernel, dim3((int)(XS_ELEMS / 8 / 256)), dim3(256),
                           0, stream, X, Xs);
        hipLaunchKernelGGL(convert_kernel, dim3((int)(WS_ELEMS / 8 / 256)), dim3(256),
                           0, stream, W, Ws);
        hipLaunchKernelGGL(gemm_a2a_kernel, dim3(NWG), dim3(512), 0, stream, Xs, Ws, out);
    } else {
        hipLaunchKernelGGL(gemm_a2a_f32_kernel, dim3(FNWG), dim3(256), 0, stream, X, W, out);
    }
}

// Round 15
// 381.327 us; speedup vs baseline: 2.0822x; 1.1725x over previous
//
#include <hip/hip_runtime.h>

// SPModel_6846177870356: y = x@W^T + all2all permute. M=28160, N=K=2048.
// Inputs FP32 (harness-upcast fp16), output FP32.
// Round 15: R14 ledger + m201 phase skeleton — reads PRE-barrier, double
// barrier per phase, lgkmcnt(0)+sched_barrier after barrier (rule #18),
// counted vmcnt 6/6/-/4 (never <4 in loop). 4 quadrant-phases per K-tile.
// 256x256, BK=64, dbuf 128KB, 8 waves (2Mx4N), pre-swizzled f16 globals (R9),
// conflict-free XOR ds_read (T2), setprio (T5), XCD swizzle (T1), fused a2a.

typedef _Float16 f16;
typedef _Float16 f16x2 __attribute__((ext_vector_type(2)));
typedef _Float16 f16x8 __attribute__((ext_vector_type(8)));
typedef float    f32x4 __attribute__((ext_vector_type(4)));

#define GPTR(p) ((const __attribute__((address_space(1))) void*)(p))
#define LPTR(p) ((__attribute__((address_space(3))) void*)(p))

constexpr int Mdim = 28160;   // 8*44*80
constexpr int Ndim = 2048;
constexpr int Kdim = 2048;
constexpr int BM = 256, BN = 256, BK = 64;
constexpr int NWG = (Mdim / BM) * (Ndim / BN);  // 880 (%8==0)
constexpr int NT  = Kdim / BK;                  // 32
constexpr size_t XS_ELEMS = (size_t)Mdim * Kdim;
constexpr size_t WS_ELEMS = (size_t)Ndim * Kdim;
constexpr size_t WS_NEED  = (XS_ELEMS + WS_ELEMS) * sizeof(f16);

__device__ __forceinline__ f16x8 pack8(const f32x4& lo, const f32x4& hi) {
    f16x2 p0 = __builtin_bit_cast(f16x2, __builtin_amdgcn_cvt_pkrtz(lo[0], lo[1]));
    f16x2 p1 = __builtin_bit_cast(f16x2, __builtin_amdgcn_cvt_pkrtz(lo[2], lo[3]));
    f16x2 p2 = __builtin_bit_cast(f16x2, __builtin_amdgcn_cvt_pkrtz(hi[0], hi[1]));
    f16x2 p3 = __builtin_bit_cast(f16x2, __builtin_amdgcn_cvt_pkrtz(hi[2], hi[3]));
    return (f16x8){p0[0], p0[1], p1[0], p1[1], p2[0], p2[1], p3[0], p3[1]};
}

// f32 [rows x 2048] -> f16 pre-swizzled: dst[m][(k8 ^ (m&7))*8] (R9-verified).
__global__ __launch_bounds__(256)
void convert_kernel(const float* __restrict__ src, f16* __restrict__ dst) {
    const int idx = blockIdx.x * 256 + threadIdx.x;
    const int m   = idx >> 8;
    const int k8  = idx & 255;
    const int k8s = k8 ^ (m & 7);
    const float* p = src + (size_t)m * Kdim + k8 * 8;
    f32x4 lo = *(const f32x4*)p;
    f32x4 hi = *(const f32x4*)(p + 4);
    *(f16x8*)(dst + (size_t)m * Kdim + k8s * 8) = pack8(lo, hi);
}

// swizzled LDS read: row stride 128B, byte ^= (row&7)<<4 (0 conflicts)
__device__ __forceinline__ f16x8 lds_frag(const f16* base, int r, int kc) {
    const int b = ((r * BK + kc) * 2) ^ ((r & 7) << 4);
    return *(const f16x8*)((const char*)base + b);
}

__global__ __launch_bounds__(512, 2)
void gemm_a2a_kernel(const f16* __restrict__ Xs, const f16* __restrict__ Ws,
                     float* __restrict__ out) {
    __shared__ f16 sA[2][BM * BK];   // 32 KiB each, swizzled image
    __shared__ f16 sB[2][BN * BK];   // total 128 KiB

    const int tid  = threadIdx.x;
    const int lane = tid & 63;
    const int wid  = tid >> 6;
    const int wm   = wid >> 2;          // 0..1 -> 128 M-rows
    const int wn   = wid & 3;           // 0..3 -> 64 N-cols

    const int cpx  = NWG >> 3;                       // XCD-bijective swizzle
    const int tile = (blockIdx.x & 7) * cpx + (blockIdx.x >> 3);
    const int bn   = tile & 7;
    const int bm   = tile >> 3;
    const int row0 = bm * BM;
    const int col0 = bn * BN;

    const int lr = lane & 15;
    const int kq = (lane >> 4) * 8;

    f32x4 acc[8][4] = {};

    // staging units (R14-verified mapping): A_u by qm-halves, B_u by qn-halves
    const f16* srcA[2][2]; const f16* srcB[2][2];
    int dstA[2][2], dstB[2][2];
#pragma unroll
    for (int u = 0; u < 2; ++u)
#pragma unroll
        for (int g = 0; g < 2; ++g) {
            const int L  = g * 512 + tid;
            const int rl = L >> 3;
            const int ka = (L & 7) * 8;
            const int ra = (rl & 63) + u * 64 + ((rl & 64) << 1);
            const int rb = (rl & 31) + u * 32 + ((rl >> 5) << 6);
            srcA[u][g] = Xs + (size_t)(row0 + ra) * Kdim + ka;
            srcB[u][g] = Ws + (size_t)(col0 + rb) * Kdim + ka;
            dstA[u][g] = (ra * 8 + (L & 7)) * 8;
            dstB[u][g] = (rb * 8 + (L & 7)) * 8;
        }

#define STAGE_A(T, D, U)                                                     \
    do {                                                                     \
        __builtin_amdgcn_global_load_lds(GPTR(srcA[U][0] + (T) * BK),        \
            LPTR(&sA[D][dstA[U][0]]), 16, 0, 0);                             \
        __builtin_amdgcn_global_load_lds(GPTR(srcA[U][1] + (T) * BK),        \
            LPTR(&sA[D][dstA[U][1]]), 16, 0, 0);                             \
    } while (0)
#define STAGE_B(T, D, U)                                                     \
    do {                                                                     \
        __builtin_amdgcn_global_load_lds(GPTR(srcB[U][0] + (T) * BK),        \
            LPTR(&sB[D][dstB[U][0]]), 16, 0, 0);                             \
        __builtin_amdgcn_global_load_lds(GPTR(srcB[U][1] + (T) * BK),        \
            LPTR(&sB[D][dstB[U][1]]), 16, 0, 0);                             \
    } while (0)

    f16x8 Af[4][2], Bf0[2][2], Bf1[2][2];
    auto readA = [&](const f16* base, int qm) {
#pragma unroll
        for (int f = 0; f < 4; ++f)
#pragma unroll
            for (int kk = 0; kk < 2; ++kk)
                Af[f][kk] = lds_frag(base, wm * 128 + qm * 64 + f * 16 + lr,
                                     kk * 32 + kq);
    };
    auto readB = [&](const f16* base, int qn, f16x8 (&dst)[2][2]) {
#pragma unroll
        for (int g = 0; g < 2; ++g)
#pragma unroll
            for (int kk = 0; kk < 2; ++kk)
                dst[g][kk] = lds_frag(base, wn * 64 + qn * 32 + g * 16 + lr,
                                      kk * 32 + kq);
    };

#define MFMA16(BARR, QM, QN)                                                 \
    do {                                                                     \
        __builtin_amdgcn_s_setprio(1);                                       \
        _Pragma("unroll")                                                    \
        for (int kk = 0; kk < 2; ++kk)                                       \
            _Pragma("unroll")                                                \
            for (int f = 0; f < 4; ++f)                                      \
                _Pragma("unroll")                                            \
                for (int g = 0; g < 2; ++g)                                  \
                    acc[(QM)*4 + f][(QN)*2 + g] =                            \
                        __builtin_amdgcn_mfma_f32_16x16x32_f16(              \
                            Af[f][kk], BARR[g][kk],                          \
                            acc[(QM)*4 + f][(QN)*2 + g], 0, 0, 0);           \
        __builtin_amdgcn_s_setprio(0);                                       \
    } while (0)

#define VM(N)   asm volatile("s_waitcnt vmcnt(" #N ")" ::: "memory")
#define BAR()   __builtin_amdgcn_s_barrier()
#define LGKM0() do { asm volatile("s_waitcnt lgkmcnt(0)" ::: "memory");      \
                     __builtin_amdgcn_sched_barrier(0); } while (0)

    // Prologue: stage tile 0 fully; certify A0,B0(0) (A1,B1 keep flying).
    STAGE_A(0, 0, 0); STAGE_B(0, 0, 0); STAGE_A(0, 0, 1); STAGE_B(0, 0, 1);
    VM(4); BAR();

    for (int t = 0; t < NT - 1; ++t) {
        const int d  = t & 1;
        const int dn = d ^ 1;
        const int tn = t + 1;
        const f16* Ab = sA[d];
        const f16* Bb = sB[d];
        // p0: q(0,0) — reads certified by p3(t-1)/prologue gate
        readA(Ab, 0); readB(Bb, 0, Bf0);
        STAGE_A(tn, dn, 0); STAGE_B(tn, dn, 0);
        VM(6); BAR(); LGKM0();           // certifies A1(t)
        MFMA16(Bf0, 0, 0);
        BAR();
        // p1: q(1,0)
        readA(Ab, 1);
        STAGE_A(tn, dn, 1);
        VM(6); BAR(); LGKM0();           // certifies B1(t)
        MFMA16(Bf0, 1, 0);
        BAR();
        // p2: q(1,1)
        readB(Bb, 1, Bf1);
        STAGE_B(tn, dn, 1);
        BAR(); LGKM0();                  // no vmcnt needed
        MFMA16(Bf1, 1, 1);
        BAR();
        // p3: q(0,1) — A re-read (long certified)
        readA(Ab, 0);
        VM(4); BAR(); LGKM0();           // certifies A0,B0(t+1)
        MFMA16(Bf1, 0, 1);
        BAR();
    }

    // Peeled last tile: no staging; gates vmcnt(2)/(0).
    {
        const f16* Ab = sA[(NT - 1) & 1];
        const f16* Bb = sB[(NT - 1) & 1];
        readA(Ab, 0); readB(Bb, 0, Bf0);
        VM(2); BAR(); LGKM0();
        MFMA16(Bf0, 0, 0);
        BAR();
        readA(Ab, 1);
        VM(0); BAR(); LGKM0();
        MFMA16(Bf0, 1, 0);
        BAR();
        readB(Bb, 1, Bf1);
        BAR(); LGKM0();
        MFMA16(Bf1, 1, 1);
        BAR();
        readA(Ab, 0);
        LGKM0();
        MFMA16(Bf1, 0, 1);
    }

    // Epilogue: C/D col=lane&15 (n), row=(lane>>4)*4+j (m); fused all2all:
    // out[(n>>8)*M*256 + m*256 + (n&255)], f32 stores.
    const int R0 = row0 + wm * 128;
    const int C0 = col0 + wn * 64;
#pragma unroll
    for (int mi = 0; mi < 8; ++mi)
#pragma unroll
        for (int ni = 0; ni < 4; ++ni) {
            const int n     = C0 + ni * 16 + (lane & 15);
            const int rbase = R0 + mi * 16 + (lane >> 4) * 4;
            const size_t obase = (size_t)(n >> 8) * ((size_t)Mdim * 256) + (n & 255);
#pragma unroll
            for (int j = 0; j < 4; ++j)
                out[obase + (size_t)(rbase + j) * 256] = acc[mi][ni][j];
        }
}

// ---- Fallback (R7-verified): direct-f32 reg-staged dbuf 128^2 kernel ----
constexpr int FBM = 128, FBK = 64;
constexpr int FNWG = (Mdim / FBM) * (Ndim / FBM);
__global__ __launch_bounds__(256)
void gemm_a2a_f32_kernel(const float* __restrict__ X, const float* __restrict__ W,
                         float* __restrict__ out) {
    __shared__ f16 sA[2][FBM * FBK];
    __shared__ f16 sB[2][FBM * FBK];
    const int tid  = threadIdx.x;
    const int lane = tid & 63;
    const int wid  = tid >> 6;
    const int wr   = wid >> 1;
    const int wc   = wid & 1;
    const int cpx  = FNWG >> 3;
    const int tile = (blockIdx.x & 7) * cpx + (blockIdx.x >> 3);
    const int bn   = tile & 15;
    const int bm   = tile >> 4;
    const int row0 = bm * FBM;
    const int col0 = bn * FBM;
    f32x4 acc[4][4] = {};
    f32x4 ra[8], rb[8];
    auto load_tile = [&](int t) {
#pragma unroll
        for (int i = 0; i < 4; ++i) {
            const int c8 = i * 256 + tid;
            const int r  = c8 >> 3;
            const int cc = (c8 & 7) * 8;
            const float* pa = X + (size_t)(row0 + r) * Kdim + t * FBK + cc;
            const float* pb = W + (size_t)(col0 + r) * Kdim + t * FBK + cc;
            ra[2*i] = *(const f32x4*)pa; ra[2*i+1] = *(const f32x4*)(pa + 4);
            rb[2*i] = *(const f32x4*)pb; rb[2*i+1] = *(const f32x4*)(pb + 4);
        }
    };
    int cur = 0;
    load_tile(0);
    for (int t = 0; t < Kdim / FBK; ++t) {
#pragma unroll
        for (int i = 0; i < 4; ++i) {
            const int c8 = i * 256 + tid;
            const int sb = (c8 * 16) ^ (((c8 >> 3) & 7) << 4);
            *(f16x8*)((char*)sA[cur] + sb) = pack8(ra[2*i], ra[2*i+1]);
            *(f16x8*)((char*)sB[cur] + sb) = pack8(rb[2*i], rb[2*i+1]);
        }
        if (t + 1 < Kdim / FBK) load_tile(t + 1);
        __syncthreads();
        const f16* Ab = sA[cur];
        const f16* Bb = sB[cur];
#pragma unroll
        for (int kk = 0; kk < FBK; kk += 32) {
            const int kc = kk + (lane >> 4) * 8;
            f16x8 af[4], bfr[4];
#pragma unroll
            for (int f = 0; f < 4; ++f) {
                const int rowA = wr * 64 + f * 16 + (lane & 15);
                af[f] = *(const f16x8*)((const char*)Ab + (((rowA * FBK + kc) * 2) ^ ((rowA & 7) << 4)));
                const int rowB = wc * 64 + f * 16 + (lane & 15);
                bfr[f] = *(const f16x8*)((const char*)Bb + (((rowB * FBK + kc) * 2) ^ ((rowB & 7) << 4)));
            }
#pragma unroll
            for (int mi = 0; mi < 4; ++mi)
#pragma unroll
                for (int ni = 0; ni < 4; ++ni)
                    acc[mi][ni] = __builtin_amdgcn_mfma_f32_16x16x32_f16(
                        af[mi], bfr[ni], acc[mi][ni], 0, 0, 0);
        }
        cur ^= 1;
    }
#pragma unroll
    for (int mi = 0; mi < 4; ++mi)
#pragma unroll
        for (int ni = 0; ni < 4; ++ni) {
            const int n     = col0 + wc * 64 + ni * 16 + (lane & 15);
            const int rbase = row0 + wr * 64 + mi * 16 + (lane >> 4) * 4;
            const size_t obase = (size_t)(n >> 8) * ((size_t)Mdim * 256) + (n & 255);
#pragma unroll
            for (int j = 0; j < 4; ++j)
                out[obase + (size_t)(rbase + j) * 256] = acc[mi][ni][j];
        }
}

extern "C" void kernel_launch(void* const* d_in, const int* in_sizes, int n_in,
                              void* d_out, int out_size, void* d_ws, size_t ws_size,
                              hipStream_t stream) {
    const float* X = (const float*)d_in[0];
    const float* W = (const float*)d_in[1];
    float* out     = (float*)d_out;
    if (ws_size >= WS_NEED) {
        f16* Xs = (f16*)d_ws;
        f16* Ws = Xs + XS_ELEMS;
        hipLaunchKernelGGL(convert_kernel, dim3((int)(XS_ELEMS / 8 / 256)), dim3(256),
                           0, stream, X, Xs);
        hipLaunchKernelGGL(convert_kernel, dim3((int)(WS_ELEMS / 8 / 256)), dim3(256),
                           0, stream, W, Ws);
        hipLaunchKernelGGL(gemm_a2a_kernel, dim3(NWG), dim3(512), 0, stream, Xs, Ws, out);
    } else {
        hipLaunchKernelGGL(gemm_a2a_f32_kernel, dim3(FNWG), dim3(256), 0, stream, X, W, out);
    }
}